// Round 3
// baseline (140.039 us; speedup 1.0000x reference)
//
#include <hip/hip_runtime.h>
#include <math.h>

constexpr int N_ELEM = 8192;
constexpr int BLK    = 256;
constexpr int NBLK   = N_ELEM / BLK;      // 32
constexpr float LAMBDA = 0.1f;

constexpr int K2_IPB  = 8;                // i-rows per block
constexpr int K2_GRID = N_ELEM / K2_IPB;  // 1024 blocks (~half exit early)

// ws layout (bytes):
//   [0,8)        int cnt, int done                (memset 256B covers)
//   [256, 2304)  double part[32][8]  {bce,W,S1a,S2a,S1b,S2b,-,-}  plain stores
//   [4096, +64K) double gpart[1024][8] {P,Ra1,Ra2,Rb1,Rb2,Rab,-,-} plain stores
//   [69632, +128K) float4 c[8192] compacted (v1,v2,w,0); beyond cnt = garbage, masked
// total ~198 KB

// K1: BCE + masked moments (per-block partials, no atomics except cnt) + compaction
__global__ void __launch_bounds__(BLK) k1_init(
        const float* __restrict__ inf, const int* __restrict__ lab,
        const float* __restrict__ tgt, const float* __restrict__ wt,
        int* __restrict__ cnt, double* __restrict__ part, float4* __restrict__ c) {
    __shared__ float red[4][8];
    int tx = threadIdx.x;
    int i = blockIdx.x * BLK + tx;
    float p = inf[i];
    int   y = lab[i];
    float w = wt[i];
    float t = tgt[i];

    float logp   = fmaxf(logf(p),    -100.0f);
    float log1mp = fmaxf(log1pf(-p), -100.0f);
    float yf = (float)y;
    float bce = w * -(yf * logp + (1.0f - yf) * log1mp);

    bool  m  = (y == 0);
    float wm = m ? w : 0.0f;

    // wave-aggregated compaction (order irrelevant: downstream sums symmetric)
    unsigned long long bal = __ballot(m);
    int lane = tx & 63, wid = tx >> 6;
    int pre  = __popcll(bal & ((1ull << lane) - 1ull));
    int wcnt = __popcll(bal);
    int base = 0;
    if (lane == 0) base = atomicAdd(cnt, wcnt);
    base = __shfl(base, 0);
    if (m) c[base + pre] = make_float4(p, t, w, 0.0f);

    float v[6] = {bce, wm, wm * p, wm * p * p, wm * t, wm * t * t};
#pragma unroll
    for (int k = 0; k < 6; ++k) {
        float s = v[k];
#pragma unroll
        for (int d = 32; d > 0; d >>= 1) s += __shfl_xor(s, d);
        if (lane == 0) red[wid][k] = s;
    }
    __syncthreads();
    if (tx < 6) {
        double s = (double)red[0][tx] + (double)red[1][tx]
                 + (double)red[2][tx] + (double)red[3][tx];
        part[blockIdx.x * 8 + tx] = s;
    }
}

// K2: each block owns K2_IPB complete rows; threads stripe over j.
// Produces per-block {P,Ra1,Ra2,Rb1,Rb2,Rab}; last block assembles outputs.
__global__ void __launch_bounds__(BLK) k2_pairs(
        const float4* __restrict__ c, const int* __restrict__ cnt,
        int* __restrict__ done, double* __restrict__ gpart,
        const double* __restrict__ part, float* __restrict__ out) {
    __shared__ float4 si[K2_IPB];
    __shared__ float red[4][24];
    __shared__ float totS[24];
    __shared__ int lastFlag;

    int tx = threadIdx.x;
    int lane = tx & 63, wid = tx >> 6;
    int nc = *cnt;
    int iBase = blockIdx.x * K2_IPB;
    double* myg = gpart + (size_t)blockIdx.x * 8;

    if (iBase < nc) {
        if (tx < K2_IPB) si[tx] = c[iBase + tx];
        __syncthreads();
        float xi[K2_IPB], yi[K2_IPB];
#pragma unroll
        for (int k = 0; k < K2_IPB; ++k) { xi[k] = si[k].x; yi[k] = si[k].y; }

        float ra[K2_IPB] = {0}, rb[K2_IPB] = {0}, pp[K2_IPB] = {0};
        int iters = (nc + BLK - 1) >> 8;
#pragma unroll 2
        for (int j0 = 0; j0 < iters; ++j0) {
            int j = j0 * BLK + tx;
            float4 cj = c[j];                       // j < 8192 always: no OOB
            float uj = (j < nc) ? cj.z : 0.0f;      // mask pad
#pragma unroll
            for (int k = 0; k < K2_IPB; ++k) {
                float f1 = fabsf(xi[k] - cj.x);
                float f2 = fabsf(yi[k] - cj.y);
                ra[k] = fmaf(uj, f1, ra[k]);
                rb[k] = fmaf(uj, f2, rb[k]);
                pp[k] = fmaf(uj, f1 * f2, pp[k]);
            }
        }
        // block-reduce 24 partials: wave butterfly then cross-wave via LDS
#pragma unroll
        for (int k = 0; k < K2_IPB; ++k) {
            float s0 = ra[k], s1 = rb[k], s2 = pp[k];
#pragma unroll
            for (int d = 32; d > 0; d >>= 1) {
                s0 += __shfl_xor(s0, d);
                s1 += __shfl_xor(s1, d);
                s2 += __shfl_xor(s2, d);
            }
            if (lane == 0) { red[wid][k] = s0; red[wid][8 + k] = s1; red[wid][16 + k] = s2; }
        }
        __syncthreads();
        if (tx < 24)
            totS[tx] = red[0][tx] + red[1][tx] + red[2][tx] + red[3][tx];
        __syncthreads();
        if (tx == 0) {
            double P = 0, Ra1 = 0, Ra2 = 0, Rb1 = 0, Rb2 = 0, Rab = 0;
#pragma unroll
            for (int k = 0; k < K2_IPB; ++k) {
                double w   = (iBase + k < nc) ? (double)si[k].z : 0.0;
                double rak = totS[k], rbk = totS[8 + k], ppk = totS[16 + k];
                Ra1 += w * rak;        Ra2 += w * rak * rak;
                Rb1 += w * rbk;        Rb2 += w * rbk * rbk;
                Rab += w * rak * rbk;  P   += w * ppk;
            }
            myg[0] = P; myg[1] = Ra1; myg[2] = Ra2;
            myg[3] = Rb1; myg[4] = Rb2; myg[5] = Rab;
        }
    } else {
        if (tx == 0) {
            myg[0] = 0; myg[1] = 0; myg[2] = 0; myg[3] = 0; myg[4] = 0; myg[5] = 0;
        }
    }

    // completion count; last block finalizes
    __threadfence();
    if (tx == 0) {
        int old = atomicAdd(done, 1);
        lastFlag = (old == K2_GRID - 1);
    }
    __syncthreads();
    if (!lastFlag) return;

    // cooperative sum of gpart[1024][6] (written device-wide; fenced before done++)
    __shared__ double dred[4][6];
    double acc[6] = {0, 0, 0, 0, 0, 0};
    for (int r = tx; r < K2_GRID; r += BLK) {
        const double* gp = gpart + (size_t)r * 8;
#pragma unroll
        for (int k = 0; k < 6; ++k) acc[k] += gp[k];
    }
#pragma unroll
    for (int k = 0; k < 6; ++k) {
        double s = acc[k];
#pragma unroll
        for (int d = 32; d > 0; d >>= 1) s += __shfl_xor(s, d);
        if (lane == 0) dred[wid][k] = s;
    }
    __syncthreads();
    if (tx == 0) {
        double P   = dred[0][0] + dred[1][0] + dred[2][0] + dred[3][0];
        double Ra1 = dred[0][1] + dred[1][1] + dred[2][1] + dred[3][1];
        double Ra2 = dred[0][2] + dred[1][2] + dred[2][2] + dred[3][2];
        double Rb1 = dred[0][3] + dred[1][3] + dred[2][3] + dred[3][3];
        double Rb2 = dred[0][4] + dred[1][4] + dred[2][4] + dred[3][4];
        double Rab = dred[0][5] + dred[1][5] + dred[2][5] + dred[3][5];

        double bceS = 0, W = 0, S1a = 0, S2a = 0, S1b = 0, S2b = 0;
        for (int b = 0; b < NBLK; ++b) {
            const double* pb = part + b * 8;
            bceS += pb[0]; W += pb[1]; S1a += pb[2];
            S2a += pb[3]; S1b += pb[4]; S2b += pb[5];
        }

        double nf = (double)nc;
        double n2 = nf * nf, n3 = n2 * nf, n4 = n2 * n2;

        double AAa = 2.0 * (W * S2a - S1a * S1a)
                   - 4.0 * Ra2 / nf + 2.0 * W * Ra2 / n2
                   + 4.0 * Ra1 * Ra1 / n2 - 4.0 * W * Ra1 * Ra1 / n3
                   + W * W * Ra1 * Ra1 / n4;
        double BBa = 2.0 * (W * S2b - S1b * S1b)
                   - 4.0 * Rb2 / nf + 2.0 * W * Rb2 / n2
                   + 4.0 * Rb1 * Rb1 / n2 - 4.0 * W * Rb1 * Rb1 / n3
                   + W * W * Rb1 * Rb1 / n4;
        double ABa = P
                   - 4.0 * Rab / nf + 2.0 * W * Rab / n2
                   + 4.0 * Ra1 * Rb1 / n2 - 4.0 * W * Ra1 * Rb1 / n3
                   + W * W * Ra1 * Rb1 / n4;

        double AB = ABa / n2, AA = AAa / n2, BB = BBa / n2;
        double dcorr = (AB * AB) / (AA * BB);
        double ld = (double)LAMBDA * dcorr;
        double bce = bceS / (double)N_ELEM;
        out[0] = (float)(bce + ld);
        out[1] = (float)bce;
        out[2] = (float)ld;
    }
}

extern "C" void kernel_launch(void* const* d_in, const int* in_sizes, int n_in,
                              void* d_out, int out_size, void* d_ws, size_t ws_size,
                              hipStream_t stream) {
    const float* inf = (const float*)d_in[0];
    const int*   lab = (const int*)d_in[1];
    const float* tgt = (const float*)d_in[2];
    const float* wt  = (const float*)d_in[3];
    float* out = (float*)d_out;

    int*    cnt   = (int*)d_ws;
    int*    done  = cnt + 1;
    double* part  = (double*)((char*)d_ws + 256);
    double* gpart = (double*)((char*)d_ws + 4096);
    float4* c     = (float4*)((char*)d_ws + 4096 + (size_t)K2_GRID * 8 * sizeof(double));

    hipMemsetAsync(d_ws, 0, 256, stream);
    k1_init<<<NBLK, BLK, 0, stream>>>(inf, lab, tgt, wt, cnt, part, c);
    k2_pairs<<<K2_GRID, BLK, 0, stream>>>(c, cnt, done, gpart, part, out);
}

// Round 4
// 85.906 us; speedup vs baseline: 1.6302x; 1.6302x over previous
//
#include <hip/hip_runtime.h>
#include <math.h>

constexpr int N_ELEM = 8192;
constexpr int BLK    = 256;
constexpr int K1_GRID = N_ELEM / BLK;          // 32
constexpr int WAVES_PER_BLK = 4;               // 256 threads
constexpr int ROWS_PER_WAVE = 2;
constexpr int ROWS_PER_BLK  = WAVES_PER_BLK * ROWS_PER_WAVE;  // 8
constexpr int K2_GRID = N_ELEM / ROWS_PER_BLK; // 1024
constexpr float LAMBDA = 0.1f;

// ws layout (all slots written every call; NO memset, NO atomics anywhere):
//   [0, 2048)          double part[32][8]   {bce, nf, W, S1a, S2a, S1b, S2b, unused}
//   [2048, 51200)      double gpart[1024][6] {P, Ra1, Ra2, Rb1, Rb2, Rab}
//   [51200, 182272)    float4 c[8192]       (p, t, wm, 0)
constexpr size_t OFF_GPART = 2048;
constexpr size_t OFF_C     = 51200;

// K1: BCE + moment partials (plain stores) + packed (p,t,wm) array
__global__ void __launch_bounds__(BLK) k1_init(
        const float* __restrict__ inf, const int* __restrict__ lab,
        const float* __restrict__ tgt, const float* __restrict__ wt,
        double* __restrict__ part, float4* __restrict__ c) {
    __shared__ float red[WAVES_PER_BLK][8];
    int tx = threadIdx.x;
    int lane = tx & 63, wid = tx >> 6;
    int i = blockIdx.x * BLK + tx;

    float p = inf[i];
    int   y = lab[i];
    float w = wt[i];
    float t = tgt[i];

    float logp   = fmaxf(logf(p),    -100.0f);
    float log1mp = fmaxf(log1pf(-p), -100.0f);
    float yf = (float)y;
    float bce = w * -(yf * logp + (1.0f - yf) * log1mp);

    bool  m  = (y == 0);
    float mf = m ? 1.0f : 0.0f;
    float wm = m ? w : 0.0f;

    c[i] = make_float4(p, t, wm, 0.0f);

    float v[7] = {bce, mf, wm, wm * p, wm * p * p, wm * t, wm * t * t};
#pragma unroll
    for (int k = 0; k < 7; ++k) {
        float s = v[k];
#pragma unroll
        for (int d = 32; d > 0; d >>= 1) s += __shfl_xor(s, d);
        if (lane == 0) red[wid][k] = s;
    }
    __syncthreads();
    if (tx < 7) {
        double s = (double)red[0][tx] + (double)red[1][tx]
                 + (double)red[2][tx] + (double)red[3][tx];
        part[blockIdx.x * 8 + tx] = s;
    }
}

// K2: each wave owns 2 complete rows; lanes stripe over j. No atomics.
__global__ void __launch_bounds__(BLK) k2_pairs(
        const float4* __restrict__ c, double* __restrict__ gpart) {
    __shared__ double sred[WAVES_PER_BLK][6];
    int tx = threadIdx.x, lane = tx & 63, wid = tx >> 6;
    int r0 = blockIdx.x * ROWS_PER_BLK + wid * ROWS_PER_WAVE;

    float4 c0 = c[r0], c1 = c[r0 + 1];
    float x0 = c0.x, y0 = c0.y, x1 = c1.x, y1 = c1.y;

    float ra0 = 0.f, rb0 = 0.f, pp0 = 0.f;
    float ra1 = 0.f, rb1 = 0.f, pp1 = 0.f;
#pragma unroll 4
    for (int jj = 0; jj < N_ELEM / 64; ++jj) {
        float4 cj = c[jj * 64 + lane];
        float u = cj.z;
        float d0 = x0 - cj.x, e0 = y0 - cj.y;
        ra0 = fmaf(u, fabsf(d0), ra0);
        rb0 = fmaf(u, fabsf(e0), rb0);
        pp0 = fmaf(u, fabsf(d0) * fabsf(e0), pp0);
        float d1 = x1 - cj.x, e1 = y1 - cj.y;
        ra1 = fmaf(u, fabsf(d1), ra1);
        rb1 = fmaf(u, fabsf(e1), rb1);
        pp1 = fmaf(u, fabsf(d1) * fabsf(e1), pp1);
    }
    // wave butterfly: finalize both row sums in-register
#pragma unroll
    for (int d = 32; d > 0; d >>= 1) {
        ra0 += __shfl_xor(ra0, d); rb0 += __shfl_xor(rb0, d); pp0 += __shfl_xor(pp0, d);
        ra1 += __shfl_xor(ra1, d); rb1 += __shfl_xor(rb1, d); pp1 += __shfl_xor(pp1, d);
    }
    if (lane == 0) {
        double u0 = (double)c0.z, u1 = (double)c1.z;
        double A0 = (double)ra0, B0 = (double)rb0, P0 = (double)pp0;
        double A1 = (double)ra1, B1 = (double)rb1, P1 = (double)pp1;
        sred[wid][0] = u0 * P0 + u1 * P1;
        sred[wid][1] = u0 * A0 + u1 * A1;
        sred[wid][2] = u0 * A0 * A0 + u1 * A1 * A1;
        sred[wid][3] = u0 * B0 + u1 * B1;
        sred[wid][4] = u0 * B0 * B0 + u1 * B1 * B1;
        sred[wid][5] = u0 * A0 * B0 + u1 * A1 * B1;
    }
    __syncthreads();
    if (tx == 0) {
        double* g = gpart + (size_t)blockIdx.x * 6;
#pragma unroll
        for (int k = 0; k < 6; ++k)
            g[k] = sred[0][k] + sred[1][k] + sred[2][k] + sred[3][k];
    }
}

// K3: single block; sum partials, assemble in f64, write outputs
__global__ void __launch_bounds__(BLK) k3_final(
        const double* __restrict__ part, const double* __restrict__ gpart,
        float* __restrict__ out) {
    __shared__ double dred[WAVES_PER_BLK][6];
    int tx = threadIdx.x, lane = tx & 63, wid = tx >> 6;

    double acc[6] = {0, 0, 0, 0, 0, 0};
    for (int r = tx; r < K2_GRID; r += BLK) {
        const double* g = gpart + (size_t)r * 6;
#pragma unroll
        for (int k = 0; k < 6; ++k) acc[k] += g[k];
    }
#pragma unroll
    for (int k = 0; k < 6; ++k) {
        double s = acc[k];
#pragma unroll
        for (int d = 32; d > 0; d >>= 1) s += __shfl_xor(s, d);
        if (lane == 0) dred[wid][k] = s;
    }
    __syncthreads();
    if (tx == 0) {
        double P   = dred[0][0] + dred[1][0] + dred[2][0] + dred[3][0];
        double Ra1 = dred[0][1] + dred[1][1] + dred[2][1] + dred[3][1];
        double Ra2 = dred[0][2] + dred[1][2] + dred[2][2] + dred[3][2];
        double Rb1 = dred[0][3] + dred[1][3] + dred[2][3] + dred[3][3];
        double Rb2 = dred[0][4] + dred[1][4] + dred[2][4] + dred[3][4];
        double Rab = dred[0][5] + dred[1][5] + dred[2][5] + dred[3][5];

        double bceS = 0, NF = 0, W = 0, S1a = 0, S2a = 0, S1b = 0, S2b = 0;
        for (int b = 0; b < K1_GRID; ++b) {
            const double* pb = part + b * 8;
            bceS += pb[0]; NF += pb[1]; W += pb[2];
            S1a += pb[3]; S2a += pb[4]; S1b += pb[5]; S2b += pb[6];
        }

        double nf = NF;
        double in1 = 1.0 / nf;
        double in2 = in1 * in1, in3 = in2 * in1, in4 = in2 * in2;

        double AAa = 2.0 * (W * S2a - S1a * S1a)
                   - 4.0 * Ra2 * in1 + 2.0 * W * Ra2 * in2
                   + 4.0 * Ra1 * Ra1 * in2 - 4.0 * W * Ra1 * Ra1 * in3
                   + W * W * Ra1 * Ra1 * in4;
        double BBa = 2.0 * (W * S2b - S1b * S1b)
                   - 4.0 * Rb2 * in1 + 2.0 * W * Rb2 * in2
                   + 4.0 * Rb1 * Rb1 * in2 - 4.0 * W * Rb1 * Rb1 * in3
                   + W * W * Rb1 * Rb1 * in4;
        double ABa = P
                   - 4.0 * Rab * in1 + 2.0 * W * Rab * in2
                   + 4.0 * Ra1 * Rb1 * in2 - 4.0 * W * Ra1 * Rb1 * in3
                   + W * W * Ra1 * Rb1 * in4;

        double AB = ABa * in2, AA = AAa * in2, BB = BBa * in2;
        double dcorr = (AB * AB) / (AA * BB);
        double ld = (double)LAMBDA * dcorr;
        double bce = bceS / (double)N_ELEM;
        out[0] = (float)(bce + ld);
        out[1] = (float)bce;
        out[2] = (float)ld;
    }
}

extern "C" void kernel_launch(void* const* d_in, const int* in_sizes, int n_in,
                              void* d_out, int out_size, void* d_ws, size_t ws_size,
                              hipStream_t stream) {
    const float* inf = (const float*)d_in[0];
    const int*   lab = (const int*)d_in[1];
    const float* tgt = (const float*)d_in[2];
    const float* wt  = (const float*)d_in[3];
    float* out = (float*)d_out;

    double* part  = (double*)d_ws;
    double* gpart = (double*)((char*)d_ws + OFF_GPART);
    float4* c     = (float4*)((char*)d_ws + OFF_C);

    k1_init<<<K1_GRID, BLK, 0, stream>>>(inf, lab, tgt, wt, part, c);
    k2_pairs<<<K2_GRID, BLK, 0, stream>>>(c, gpart);
    k3_final<<<1, BLK, 0, stream>>>(part, gpart, out);
}